// Round 2
// baseline (162.563 us; speedup 1.0000x reference)
//
#include <hip/hip_runtime.h>
#include <float.h>

#define OUT 7

// One thread per (roi, channel). C == 512 is a multiple of 64, so every
// 64-lane wave covers 64 channels of the SAME ROI: all loop bounds are
// wave-uniform (scalar branches, zero divergence). Each thread computes
// all 49 outputs of its (r,c) separably:
//   per feature row h: rm[7] = per-w-bin max (bins are <=3 cells)
//   fold rm into acc[oh][*] for the 1-2 h-bins containing h.
// All arrays are statically indexed inside #pragma unroll -> registers.
__global__ __launch_bounds__(256) void roi_pool_kernel(
    const float* __restrict__ features,   // [C, H, W]
    const int4*  __restrict__ rois,       // [R] of (x1,y1,x2,y2) image-pixel
    float* __restrict__ out,              // [R, C, 7, 7]
    int total, int H, int W)
{
    int t = blockIdx.x * blockDim.x + threadIdx.x;   // t = r*C + c
    if (t >= total) return;
    int c = t & 511;          // C == 512
    int r = t >> 9;

    int4 roi = rois[r];
    // (x * 1/16.f) truncated == x >> 4 for x in [0,1024): exact in fp32.
    int x1 = roi.x >> 4, y1 = roi.y >> 4, x2 = roi.z >> 4, y2 = roi.w >> 4;
    int h_len = y2 - y1 + 1;
    int w_len = x2 - x1 + 1;

    // torch adaptive bins: [floor(i*L/7), ceil((i+1)*L/7)) + offset
    int hs[OUT], he[OUT], wss[OUT], wee[OUT];
#pragma unroll
    for (int i = 0; i < OUT; ++i) {
        hs[i]  = y1 + (i * h_len) / OUT;
        he[i]  = y1 + ((i + 1) * h_len + (OUT - 1)) / OUT;
        wss[i] = x1 + (i * w_len) / OUT;
        wee[i] = x1 + ((i + 1) * w_len + (OUT - 1)) / OUT;
        if (he[i]  > H) he[i]  = H;     // reference masks clip to grid
        if (wee[i] > W) wee[i] = W;
    }

    const float* fc = features + (size_t)c * (H * W);

    float acc[OUT][OUT];
#pragma unroll
    for (int i = 0; i < OUT; ++i)
#pragma unroll
        for (int j = 0; j < OUT; ++j) acc[i][j] = -FLT_MAX;

    int hmax = y2 < H - 1 ? y2 : H - 1;
    for (int h = y1; h <= hmax; ++h) {        // uniform trip count per wave
        const float* row = fc + h * W;
        float rm[OUT];
#pragma unroll
        for (int j = 0; j < OUT; ++j) {
            float m = -FLT_MAX;
            for (int w = wss[j]; w < wee[j]; ++w) {   // uniform, <=3 iters
                float v = row[w];
                m = v > m ? v : m;
            }
            rm[j] = m;
        }
#pragma unroll
        for (int i = 0; i < OUT; ++i) {
            if (h >= hs[i] && h < he[i]) {            // uniform predicate
#pragma unroll
                for (int j = 0; j < OUT; ++j)
                    acc[i][j] = rm[j] > acc[i][j] ? rm[j] : acc[i][j];
            }
        }
    }

    float* o = out + (size_t)t * (OUT * OUT);
#pragma unroll
    for (int i = 0; i < OUT; ++i)
#pragma unroll
        for (int j = 0; j < OUT; ++j)
            o[i * OUT + j] = acc[i][j];
}

extern "C" void kernel_launch(void* const* d_in, const int* in_sizes, int n_in,
                              void* d_out, int out_size, void* d_ws, size_t ws_size,
                              hipStream_t stream) {
    const float* features = (const float*)d_in[0];   // [1,512,64,64] fp32
    const int4*  rois     = (const int4*)d_in[1];    // [R,4] int32
    float* out = (float*)d_out;

    const int H = 64, W = 64;
    int total = out_size / (OUT * OUT);              // R*C threads

    int threads = 256;
    int blocks = (total + threads - 1) / threads;
    roi_pool_kernel<<<blocks, threads, 0, stream>>>(features, rois, out, total, H, W);
}

// Round 3
// 142.903 us; speedup vs baseline: 1.1376x; 1.1376x over previous
//
#include <hip/hip_runtime.h>
#include <float.h>

// ROI max-pool to 7x7, features [512,64,64] fp32, 1024 ROIs.
//
// One WAVE per (roi, 32-channel chunk). readfirstlane(wid) makes the ROI
// index scalar -> rois[r] is an s_load, all ROI/bin-size math is SGPR, and
// the mh/mw guards below are uniform scalar branches (no exec-mask churn).
// Lane = bin (49 active of 64). Each lane precomputes its <=3x3 CLAMPED
// cell byte-offsets once (duplicated cells for 1-2 wide bins: max over
// duplicates is identity), then loops channels: feature base advances by a
// scalar add (global_load v, voff, s[base] form), ~mh*mw loads + maxes +
// one coalesced 196B store per iteration.
constexpr int CC = 512, HH = 64, WW = 64;
constexpr int NCHUNK = 16;               // chunks per ROI
constexpr int CPW = CC / NCHUNK;         // 32 channels per wave

__global__ __launch_bounds__(256) void roi_pool_kernel(
    const float* __restrict__ features,  // [C,H,W]
    const int4*  __restrict__ rois,      // [R] (x1,y1,x2,y2) image px
    float* __restrict__ out,             // [R,C,7,7]
    int ngroups)
{
    int wid = blockIdx.x * (blockDim.x >> 6) + (threadIdx.x >> 6);
    wid = __builtin_amdgcn_readfirstlane(wid);   // wave-uniform -> SGPR
    if (wid >= ngroups) return;
    int lane = threadIdx.x & 63;

    int r  = wid >> 4;                    // / NCHUNK
    int c0 = (wid & (NCHUNK - 1)) * CPW;

    int4 roi = rois[r];                   // uniform addr -> s_load_dwordx4
    // (px * 1/16.f) truncated == px >> 4 for px in [0,1024): exact in fp32.
    int x1 = roi.x >> 4, y1 = roi.y >> 4, x2 = roi.z >> 4, y2 = roi.w >> 4;
    int h_len = y2 - y1 + 1;              // 2..9
    int w_len = x2 - x1 + 1;

    bool active = lane < 49;
    int bin = active ? lane : 0;          // idle lanes shadow lane 0 (free)
    int oh = bin / 7, ow = bin - oh * 7;

    // torch adaptive bins: [floor(i*L/7), ceil((i+1)*L/7)) + offset
    int hs = y1 + (oh * h_len) / 7;
    int he = y1 + ((oh + 1) * h_len + 6) / 7;
    int ws = x1 + (ow * w_len) / 7;
    int we = x1 + ((ow + 1) * w_len + 6) / 7;
    he = min(he, HH); we = min(we, WW);   // no-op by construction; cheap

    // Clamped cell coordinates (duplicates when bin smaller than 3x3).
    int hl = he - 1, wl = we - 1;
    int h0 = hs, h1 = min(hs + 1, hl), h2 = min(hs + 2, hl);
    int w0 = ws, w1 = min(ws + 1, wl), w2 = min(ws + 2, wl);
    int r0 = h0 * WW, r1 = h1 * WW, r2 = h2 * WW;
    // 9 byte offsets, loop-invariant VGPRs.
    int o00 = (r0 + w0) * 4, o01 = (r0 + w1) * 4, o02 = (r0 + w2) * 4;
    int o10 = (r1 + w0) * 4, o11 = (r1 + w1) * 4, o12 = (r1 + w2) * 4;
    int o20 = (r2 + w0) * 4, o21 = (r2 + w1) * 4, o22 = (r2 + w2) * 4;

    // Conservative per-ROI max bin size (uniform -> scalar branches).
    // Exact max is <= (L-1)/7 + 2, clamped to 3; over-estimate only causes
    // duplicate clamped loads (same cache line), never wrong results.
    int mh = min(3, (h_len - 1) / 7 + 2);
    int mw = min(3, (w_len - 1) / 7 + 2);
    bool mh2 = mh >= 2, mh3 = mh >= 3, mw2 = mw >= 2, mw3 = mw >= 3;

    const char* fb = (const char*)features + (size_t)c0 * (HH * WW * 4);
    float* ob = out + ((size_t)r * CC + c0) * 49;

#pragma unroll 2
    for (int j = 0; j < CPW; ++j) {
        float a = *(const float*)(fb + o00);
        if (mw2) a = fmaxf(a, *(const float*)(fb + o01));
        if (mw3) a = fmaxf(a, *(const float*)(fb + o02));
        if (mh2) {
            a = fmaxf(a, *(const float*)(fb + o10));
            if (mw2) a = fmaxf(a, *(const float*)(fb + o11));
            if (mw3) a = fmaxf(a, *(const float*)(fb + o12));
        }
        if (mh3) {
            a = fmaxf(a, *(const float*)(fb + o20));
            if (mw2) a = fmaxf(a, *(const float*)(fb + o21));
            if (mw3) a = fmaxf(a, *(const float*)(fb + o22));
        }
        if (active) ob[lane] = a;         // 196B contiguous per wave
        fb += HH * WW * 4;                // scalar adds (uniform)
        ob += 49;
    }
}

extern "C" void kernel_launch(void* const* d_in, const int* in_sizes, int n_in,
                              void* d_out, int out_size, void* d_ws, size_t ws_size,
                              hipStream_t stream) {
    const float* features = (const float*)d_in[0];   // [1,512,64,64] fp32
    const int4*  rois     = (const int4*)d_in[1];    // [R,4] int32
    float* out = (float*)d_out;

    int R = out_size / (CC * 49);                    // 1024
    int ngroups = R * NCHUNK;                        // waves
    int waves_per_block = 4;                         // 256 threads
    int blocks = (ngroups + waves_per_block - 1) / waves_per_block;
    roi_pool_kernel<<<blocks, 256, 0, stream>>>(features, rois, out, ngroups);
}

// Round 4
// 51.248 us; speedup vs baseline: 3.1721x; 2.7884x over previous
//
#include <hip/hip_runtime.h>
#include <float.h>

// ROI adaptive max-pool 7x7. features [512,64,64] fp32, 1024 ROIs.
//
// Wave = (roi, 32-channel chunk); lane = bin (lanes >=49 exit). All ROI math
// is wave-uniform (readfirstlane -> SGPR). The kernel is TA-address-rate
// bound, so each bin ROW is fetched as ONE dwordx4 (bin width <= 3 because
// w_len <= 9), junk elements masked by loop-invariant cndmasks; rows 1-2 are
// exec-predicated per lane so small bins cost fewer addresses. Channel loop
// unrolled x4 for memory-level parallelism.
constexpr int CC = 512, HH = 64, WW = 64;
constexpr int NCHUNK = 16;            // chunks per ROI
constexpr int CPW = CC / NCHUNK;      // 32 channels per wave
#define NEG (-FLT_MAX)

typedef float f4 __attribute__((ext_vector_type(4)));
typedef float uf4 __attribute__((ext_vector_type(4), aligned(4)));  // 4B-aligned loads

template <bool EDGE>
__device__ __forceinline__ void roi_loop(
    const char* fb, float* ob, int o0,
    bool need1, bool need2,
    bool m0v, bool m1v, bool m2v, bool m3v)   // element-validity masks
{
    const int o1 = o0 + WW * 4, o2 = o0 + 2 * WW * 4;
    f4 v1 = {NEG, NEG, NEG, NEG}, v2 = {NEG, NEG, NEG, NEG};
#pragma unroll 4
    for (int j = 0; j < CPW; ++j) {
        f4 v0 = *(const uf4*)(fb + o0);
        if (need1) v1 = *(const uf4*)(fb + o1);
        if (need2) v2 = *(const uf4*)(fb + o2);
        float a0, a1, a2;
        if (EDGE) {
            a0 = fmaxf(fmaxf(m0v ? v0.x : NEG, m1v ? v0.y : NEG),
                       fmaxf(m2v ? v0.z : NEG, m3v ? v0.w : NEG));
            a1 = fmaxf(fmaxf(m0v ? v1.x : NEG, m1v ? v1.y : NEG),
                       fmaxf(m2v ? v1.z : NEG, m3v ? v1.w : NEG));
            a2 = fmaxf(fmaxf(m0v ? v2.x : NEG, m1v ? v2.y : NEG),
                       fmaxf(m2v ? v2.z : NEG, m3v ? v2.w : NEG));
        } else {
            a0 = fmaxf(fmaxf(v0.x, m1v ? v0.y : NEG), m2v ? v0.z : NEG);
            a1 = fmaxf(fmaxf(v1.x, m1v ? v1.y : NEG), m2v ? v1.z : NEG);
            a2 = fmaxf(fmaxf(v2.x, m1v ? v2.y : NEG), m2v ? v2.z : NEG);
        }
        float a = fmaxf(a0, fmaxf(need1 ? a1 : NEG, need2 ? a2 : NEG));
        *ob = a;
        fb += HH * WW * 4;            // uniform scalar add
        ob += 49;
    }
}

__global__ __launch_bounds__(256) void roi_pool_kernel(
    const float* __restrict__ features,  // [C,H,W]
    const int4*  __restrict__ rois,      // [R] (x1,y1,x2,y2) image px
    float* __restrict__ out,             // [R,C,7,7]
    int ngroups)
{
    int wid = blockIdx.x * (blockDim.x >> 6) + (threadIdx.x >> 6);
    wid = __builtin_amdgcn_readfirstlane(wid);   // wave-uniform -> SGPR
    if (wid >= ngroups) return;
    int lane = threadIdx.x & 63;
    if (lane >= 49) return;           // dead lanes: no shadow addresses

    int r  = wid >> 4;                // / NCHUNK
    int c0 = (wid & (NCHUNK - 1)) * CPW;

    int4 roi = rois[r];               // uniform -> s_load_dwordx4
    // (px * 1/16.f) truncated == px >> 4 for px in [0,1024): exact in fp32.
    int x1 = roi.x >> 4, y1 = roi.y >> 4, x2 = roi.z >> 4, y2 = roi.w >> 4;
    int h_len = y2 - y1 + 1;          // 1..9  (y2 <= 63 by construction)
    int w_len = x2 - x1 + 1;          // 1..9

    int oh = lane / 7, ow = lane - oh * 7;
    // torch adaptive bins: [floor(i*L/7), ceil((i+1)*L/7)) + offset.
    // Every bin is non-empty; width <= 3, height <= 3 for L <= 9.
    int hs = y1 + (oh * h_len) / 7;
    int he = y1 + ((oh + 1) * h_len + 6) / 7;
    int ws = x1 + (ow * w_len) / 7;
    int we = x1 + ((ow + 1) * w_len + 6) / 7;

    bool need1 = hs + 1 < he;         // per-lane row predicates
    bool need2 = hs + 2 < he;

    const char* fb = (const char*)features + (size_t)c0 * (HH * WW * 4);
    float* ob = out + ((size_t)r * CC + c0) * 49 + lane;

    if (x2 <= 60) {
        // fast path: float4 at ws never crosses the buffer (ws+3 <= 63).
        // element 0 always valid, element 3 never (width <= 3).
        int o0 = (hs * WW + ws) * 4;
        bool c1 = ws + 1 < we, c2 = ws + 2 < we;
        roi_loop<false>(fb, ob, o0, need1, need2, true, c1, c2, false);
    } else {
        // edge path: clamp load base so the 16B never leaves the row range.
        int lb = min(ws, WW - 4);
        int o0 = (hs * WW + lb) * 4;
        bool k0 = (lb     >= ws);               // lb <= ws < we always
        bool k1 = (lb + 1 >= ws) && (lb + 1 < we);
        bool k2 = (lb + 2 >= ws) && (lb + 2 < we);
        bool k3 = (lb + 3 >= ws) && (lb + 3 < we);
        roi_loop<true>(fb, ob, o0, need1, need2, k0, k1, k2, k3);
    }
}

extern "C" void kernel_launch(void* const* d_in, const int* in_sizes, int n_in,
                              void* d_out, int out_size, void* d_ws, size_t ws_size,
                              hipStream_t stream) {
    const float* features = (const float*)d_in[0];   // [1,512,64,64] fp32
    const int4*  rois     = (const int4*)d_in[1];    // [R,4] int32
    float* out = (float*)d_out;

    int R = out_size / (CC * 49);                    // 1024
    int ngroups = R * NCHUNK;
    int waves_per_block = 4;                         // 256 threads
    int blocks = (ngroups + waves_per_block - 1) / waves_per_block;
    roi_pool_kernel<<<blocks, 256, 0, stream>>>(features, rois, out, ngroups);
}

// Round 5
// 39.978 us; speedup vs baseline: 4.0663x; 1.2819x over previous
//
#include <hip/hip_runtime.h>
#include <float.h>

// ROI adaptive max-pool 7x7. features [512,64,64] fp32, 1024 ROIs.
// Phase 1: transpose features to [H][W][C] (channel-contiguous) in d_ws.
// Phase 2: wave = (roi, 64 channels); lane = channel -> every load is 64
// contiguous dwords (4 cache lines/instr vs ~50 scattered in R4). All bin
// math wave-uniform (SGPR). Clamped static-3 cells per bin row: duplicates
// are identity under max -> no masks, full ILP. Store via per-wave LDS
// transpose (2 rounds x 32ch x 49) -> contiguous dwordx4 global stores.
constexpr int CC = 512, HH = 64, WW = 64, HW = HH * WW;
#define NEG (-FLT_MAX)
typedef float f4 __attribute__((ext_vector_type(4)));

// ---------- phase 1: [C][HW] -> [HW][C] ----------
__global__ __launch_bounds__(256) void transpose_kernel(
    const float* __restrict__ f, float* __restrict__ ft)
{
    __shared__ float tile[64][65];
    int bs = blockIdx.x & 63;            // hw tile (4096/64)
    int bc = blockIdx.x >> 6;            // c tile (512/64)
    int tx = threadIdx.x & 63, ty0 = threadIdx.x >> 6;
#pragma unroll
    for (int k = 0; k < 16; ++k) {
        int c = k * 4 + ty0;
        tile[c][tx] = f[(size_t)(bc * 64 + c) * HW + bs * 64 + tx];  // coalesced read
    }
    __syncthreads();
#pragma unroll
    for (int k = 0; k < 16; ++k) {
        int s = k * 4 + ty0;
        ft[(size_t)(bs * 64 + s) * CC + bc * 64 + tx] = tile[tx][s]; // coalesced write
    }
}

// ---------- phase 2: pool from [HW][C] ----------
__global__ __launch_bounds__(256) void pool_kernel(
    const float* __restrict__ ft,        // [H][W][C]
    const int4*  __restrict__ rois,      // [R] (x1,y1,x2,y2) image px
    float* __restrict__ out,             // [R,C,7,7]
    int ngroups)
{
    __shared__ __align__(16) float lds[4][32 * 49];
    int wslot = threadIdx.x >> 6;
    int wid = __builtin_amdgcn_readfirstlane(blockIdx.x * 4 + wslot);
    if (wid >= ngroups) return;
    int lane = threadIdx.x & 63;

    int r  = wid >> 3;                   // 8 channel-groups per ROI
    int c0 = (wid & 7) << 6;

    int4 roi = rois[r];                  // uniform -> s_load
    // (px * 1/16.f) truncated == px >> 4 for px in [0,1024): exact in fp32.
    int x1 = roi.x >> 4, y1 = roi.y >> 4, x2 = roi.z >> 4, y2 = roi.w >> 4;
    int hl = y2 - y1 + 1, wl = x2 - x1 + 1;   // 2..9 each

    // torch adaptive bins: [floor(i*L/7), ceil((i+1)*L/7)) + offset.
    // Clamped 3 cells per w-bin (width <= 3); duplicates are max-identity.
    int hs[7], he[7], w0[7], w1[7], w2[7];
#pragma unroll
    for (int i = 0; i < 7; ++i) {
        hs[i] = y1 + (i * hl) / 7;
        he[i] = y1 + ((i + 1) * hl + 6) / 7;
        int ws = x1 + (i * wl) / 7;
        int we = x1 + ((i + 1) * wl + 6) / 7;
        w0[i] = ws;
        w1[i] = min(ws + 1, we - 1);
        w2[i] = min(ws + 2, we - 1);
    }

    float acc[7][7];
#pragma unroll
    for (int i = 0; i < 7; ++i)
#pragma unroll
        for (int j = 0; j < 7; ++j) acc[i][j] = NEG;

    const float* fb = ft + c0 + lane;
    for (int h = y1; h <= y2; ++h) {     // uniform, 2..9 iters
        const float* rowp = fb + (size_t)h * (WW * CC);
        float m[7];
#pragma unroll
        for (int j = 0; j < 7; ++j) {    // 21 coalesced loads, full ILP
            float a = rowp[w0[j] * CC];
            float b = rowp[w1[j] * CC];
            float c = rowp[w2[j] * CC];
            m[j] = fmaxf(fmaxf(a, b), c);
        }
#pragma unroll
        for (int i = 0; i < 7; ++i) {
            if (h >= hs[i] && h < he[i]) {        // uniform scalar branch
#pragma unroll
                for (int j = 0; j < 7; ++j)
                    acc[i][j] = fmaxf(acc[i][j], m[j]);
            }
        }
    }

    // Store: transpose [64ch][49] -> flat [c][bin] via LDS, 2 rounds of 32ch.
    float* L  = lds[wslot];
    float* ob = out + ((size_t)r * CC + c0) * 49;
#pragma unroll
    for (int round = 0; round < 2; ++round) {
        if ((lane >> 5) == round) {
            float* p = L + (lane & 31) * 49;      // stride 49 (~17 mod 32): conflict-free
#pragma unroll
            for (int i = 0; i < 7; ++i)
#pragma unroll
                for (int j = 0; j < 7; ++j) p[i * 7 + j] = acc[i][j];
        }
        asm volatile("s_waitcnt lgkmcnt(0)" ::: "memory");
        float* og = ob + round * 1568;            // 1568 floats contiguous
#pragma unroll
        for (int s = 0; s < 6; ++s) {             // 6 x (64 lanes x dwordx4)
            int idx = s * 64 + lane;
            *(f4*)(og + idx * 4) = *(const f4*)(L + idx * 4);
        }
        if (lane < 8) {                           // 392 = 6*64 + 8 tail
            int idx = 384 + lane;
            *(f4*)(og + idx * 4) = *(const f4*)(L + idx * 4);
        }
        asm volatile("s_waitcnt lgkmcnt(0)" ::: "memory"); // reads done before re-write
    }
}

// ---------- fallback (R4, proven): used only if ws_size < 8 MB ----------
__global__ __launch_bounds__(256) void roi_pool_direct(
    const float* __restrict__ features, const int4* __restrict__ rois,
    float* __restrict__ out, int ngroups)
{
    int wid = __builtin_amdgcn_readfirstlane(
        blockIdx.x * (blockDim.x >> 6) + (threadIdx.x >> 6));
    if (wid >= ngroups) return;
    int lane = threadIdx.x & 63;
    if (lane >= 49) return;
    int r = wid >> 4, c0 = (wid & 15) * 32;
    int4 roi = rois[r];
    int x1 = roi.x >> 4, y1 = roi.y >> 4, x2 = roi.z >> 4, y2 = roi.w >> 4;
    int h_len = y2 - y1 + 1, w_len = x2 - x1 + 1;
    int oh = lane / 7, ow = lane - oh * 7;
    int hs = y1 + (oh * h_len) / 7, he = y1 + ((oh + 1) * h_len + 6) / 7;
    int ws = x1 + (ow * w_len) / 7, we = x1 + ((ow + 1) * w_len + 6) / 7;
    int wlst = we - 1;
    int wa = ws, wb = min(ws + 1, wlst), wc = min(ws + 2, wlst);
    bool need1 = hs + 1 < he, need2 = hs + 2 < he;
    int o0 = (hs * WW + wa) * 4, o0b = (hs * WW + wb) * 4, o0c = (hs * WW + wc) * 4;
    const char* fb = (const char*)features + (size_t)c0 * (HW * 4);
    float* ob = out + ((size_t)r * CC + c0) * 49 + lane;
#pragma unroll 4
    for (int j = 0; j < 32; ++j) {
        float a = fmaxf(fmaxf(*(const float*)(fb + o0),
                              *(const float*)(fb + o0b)),
                        *(const float*)(fb + o0c));
        if (need1) {
            a = fmaxf(a, fmaxf(fmaxf(*(const float*)(fb + o0 + WW * 4),
                                     *(const float*)(fb + o0b + WW * 4)),
                               *(const float*)(fb + o0c + WW * 4)));
        }
        if (need2) {
            a = fmaxf(a, fmaxf(fmaxf(*(const float*)(fb + o0 + 2 * WW * 4),
                                     *(const float*)(fb + o0b + 2 * WW * 4)),
                               *(const float*)(fb + o0c + 2 * WW * 4)));
        }
        *ob = a;
        fb += HW * 4;
        ob += 49;
    }
}

extern "C" void kernel_launch(void* const* d_in, const int* in_sizes, int n_in,
                              void* d_out, int out_size, void* d_ws, size_t ws_size,
                              hipStream_t stream) {
    const float* features = (const float*)d_in[0];   // [1,512,64,64] fp32
    const int4*  rois     = (const int4*)d_in[1];    // [R,4] int32
    float* out = (float*)d_out;
    int R = out_size / (CC * 49);                    // 1024

    if (ws_size >= (size_t)CC * HW * sizeof(float)) {
        float* ft = (float*)d_ws;                    // [HW][C], 8 MB
        transpose_kernel<<<512, 256, 0, stream>>>(features, ft);
        int ngroups = R * 8;                         // 64 channels per wave
        pool_kernel<<<ngroups / 4, 256, 0, stream>>>(ft, rois, out, ngroups);
    } else {
        int ngroups = R * 16;
        roi_pool_direct<<<(ngroups + 3) / 4, 256, 0, stream>>>(features, rois, out, ngroups);
    }
}

// Round 6
// 39.773 us; speedup vs baseline: 4.0873x; 1.0052x over previous
//
#include <hip/hip_runtime.h>
#include <float.h>

// ROI adaptive max-pool 7x7. features [512,64,64] fp32, 1024 ROIs.
// Phase 1: transpose features to [H][W][C] (channel-contiguous) in d_ws.
// Phase 2: wave = (roi, 64 channels); lane = channel. Per feature row:
// load each DISTINCT cell once (uniform-predicated, <=9, avg ~5 coalesced
// 64-lane loads) into registers, then build the 7 w-bin maxes with 36
// statically-unrolled wave-uniform-predicated maxes (duplicate resolution
// moved from the TA/address pipe to the idle VALU). Fold rows into h-bins
// under uniform scalar branches. Store via per-wave LDS transpose.
constexpr int CC = 512, HH = 64, WW = 64, HW = HH * WW;
#define NEG (-FLT_MAX)
typedef float f4 __attribute__((ext_vector_type(4)));

// ---------- phase 1: [C][HW] -> [HW][C] ----------
__global__ __launch_bounds__(256) void transpose_kernel(
    const float* __restrict__ f, float* __restrict__ ft)
{
    __shared__ float tile[64][65];
    int bs = blockIdx.x & 63;            // hw tile (4096/64)
    int bc = blockIdx.x >> 6;            // c tile (512/64)
    int tx = threadIdx.x & 63, ty0 = threadIdx.x >> 6;
#pragma unroll
    for (int k = 0; k < 16; ++k) {
        int c = k * 4 + ty0;
        tile[c][tx] = f[(size_t)(bc * 64 + c) * HW + bs * 64 + tx];  // coalesced read
    }
    __syncthreads();
#pragma unroll
    for (int k = 0; k < 16; ++k) {
        int s = k * 4 + ty0;
        ft[(size_t)(bs * 64 + s) * CC + bc * 64 + tx] = tile[tx][s]; // coalesced write
    }
}

// static per-bin cell ranges: bin j can only touch cells
// k in [floor(2j/7), ceil(9(j+1)/7))  for w_len in [2,9] -> 36 terms total.
#define KMIN(j) ((2 * (j)) / 7)
#define KMAX(j) ((9 * ((j) + 1) + 6) / 7)

// ---------- phase 2: pool from [HW][C] ----------
__global__ __launch_bounds__(256) void pool_kernel(
    const float* __restrict__ ft,        // [H][W][C]
    const int4*  __restrict__ rois,      // [R] (x1,y1,x2,y2) image px
    float* __restrict__ out,             // [R,C,7,7]
    int ngroups)
{
    __shared__ __align__(16) float lds[4][32 * 49];
    int wslot = threadIdx.x >> 6;
    int wid = __builtin_amdgcn_readfirstlane(blockIdx.x * 4 + wslot);
    if (wid >= ngroups) return;
    int lane = threadIdx.x & 63;

    int r  = wid >> 3;                   // 8 channel-groups per ROI
    int c0 = (wid & 7) << 6;

    int4 roi = rois[r];                  // uniform -> s_load
    // (px * 1/16.f) truncated == px >> 4 for px in [0,1024): exact in fp32.
    int x1 = roi.x >> 4, y1 = roi.y >> 4, x2 = roi.z >> 4, y2 = roi.w >> 4;
    int hl = y2 - y1 + 1, wl = x2 - x1 + 1;   // 2..9 each

    // torch adaptive bins: [floor(i*L/7), ceil((i+1)*L/7)) + offset.
    int hs[7], he[7], s_[7], e_[7];
#pragma unroll
    for (int i = 0; i < 7; ++i) {
        hs[i] = y1 + (i * hl) / 7;
        he[i] = y1 + ((i + 1) * hl + 6) / 7;
        s_[i] = (i * wl) / 7;                 // cell index relative to x1
        e_[i] = ((i + 1) * wl + 6) / 7;
    }

    float acc[7][7];
#pragma unroll
    for (int i = 0; i < 7; ++i)
#pragma unroll
        for (int j = 0; j < 7; ++j) acc[i][j] = NEG;

    const float* fb = ft + c0 + lane;
    for (int h = y1; h <= y2; ++h) {     // uniform, 2..9 iters
        const float* rowp = fb + (size_t)h * (WW * CC);
        float v[9];
#pragma unroll
        for (int k = 0; k < 9; ++k) {
            v[k] = NEG;
            if (k < wl)                  // uniform scalar branch, avg ~5 loads
                v[k] = rowp[(x1 + k) * CC];
        }
        // 7 w-bin maxes from registers: 36 uniform-predicated terms.
        float m[7];
#pragma unroll
        for (int j = 0; j < 7; ++j) {
            float a = NEG;
#pragma unroll
            for (int k = KMIN(j); k < KMAX(j); ++k) {
                bool p = (k >= s_[j]) && (k < e_[j]);   // uniform
                a = fmaxf(a, p ? v[k] : NEG);
            }
            m[j] = a;
        }
#pragma unroll
        for (int i = 0; i < 7; ++i) {
            if (h >= hs[i] && h < he[i]) {        // uniform scalar branch
#pragma unroll
                for (int j = 0; j < 7; ++j)
                    acc[i][j] = fmaxf(acc[i][j], m[j]);
            }
        }
    }

    // Store: transpose [64ch][49] -> flat [c][bin] via LDS, 2 rounds of 32ch.
    float* L  = lds[wslot];
    float* ob = out + ((size_t)r * CC + c0) * 49;
#pragma unroll
    for (int round = 0; round < 2; ++round) {
        if ((lane >> 5) == round) {
            float* p = L + (lane & 31) * 49;      // stride 49 (odd): conflict-light
#pragma unroll
            for (int i = 0; i < 7; ++i)
#pragma unroll
                for (int j = 0; j < 7; ++j) p[i * 7 + j] = acc[i][j];
        }
        asm volatile("s_waitcnt lgkmcnt(0)" ::: "memory");
        float* og = ob + round * 1568;            // 1568 floats contiguous
#pragma unroll
        for (int s = 0; s < 6; ++s) {             // 6 x (64 lanes x dwordx4)
            int idx = s * 64 + lane;
            *(f4*)(og + idx * 4) = *(const f4*)(L + idx * 4);
        }
        if (lane < 8) {                           // 392 = 6*64 + 8 tail
            int idx = 384 + lane;
            *(f4*)(og + idx * 4) = *(const f4*)(L + idx * 4);
        }
        asm volatile("s_waitcnt lgkmcnt(0)" ::: "memory"); // reads done before re-write
    }
}

// ---------- fallback (R4, proven): used only if ws_size < 8 MB ----------
__global__ __launch_bounds__(256) void roi_pool_direct(
    const float* __restrict__ features, const int4* __restrict__ rois,
    float* __restrict__ out, int ngroups)
{
    int wid = __builtin_amdgcn_readfirstlane(
        blockIdx.x * (blockDim.x >> 6) + (threadIdx.x >> 6));
    if (wid >= ngroups) return;
    int lane = threadIdx.x & 63;
    if (lane >= 49) return;
    int r = wid >> 4, c0 = (wid & 15) * 32;
    int4 roi = rois[r];
    int x1 = roi.x >> 4, y1 = roi.y >> 4, x2 = roi.z >> 4, y2 = roi.w >> 4;
    int h_len = y2 - y1 + 1, w_len = x2 - x1 + 1;
    int oh = lane / 7, ow = lane - oh * 7;
    int hs = y1 + (oh * h_len) / 7, he = y1 + ((oh + 1) * h_len + 6) / 7;
    int ws = x1 + (ow * w_len) / 7, we = x1 + ((ow + 1) * w_len + 6) / 7;
    int wlst = we - 1;
    int wa = ws, wb = min(ws + 1, wlst), wc = min(ws + 2, wlst);
    bool need1 = hs + 1 < he, need2 = hs + 2 < he;
    int o0 = (hs * WW + wa) * 4, o0b = (hs * WW + wb) * 4, o0c = (hs * WW + wc) * 4;
    const char* fb = (const char*)features + (size_t)c0 * (HW * 4);
    float* ob = out + ((size_t)r * CC + c0) * 49 + lane;
#pragma unroll 4
    for (int j = 0; j < 32; ++j) {
        float a = fmaxf(fmaxf(*(const float*)(fb + o0),
                              *(const float*)(fb + o0b)),
                        *(const float*)(fb + o0c));
        if (need1) {
            a = fmaxf(a, fmaxf(fmaxf(*(const float*)(fb + o0 + WW * 4),
                                     *(const float*)(fb + o0b + WW * 4)),
                               *(const float*)(fb + o0c + WW * 4)));
        }
        if (need2) {
            a = fmaxf(a, fmaxf(fmaxf(*(const float*)(fb + o0 + 2 * WW * 4),
                                     *(const float*)(fb + o0b + 2 * WW * 4)),
                               *(const float*)(fb + o0c + 2 * WW * 4)));
        }
        *ob = a;
        fb += HW * 4;
        ob += 49;
    }
}

extern "C" void kernel_launch(void* const* d_in, const int* in_sizes, int n_in,
                              void* d_out, int out_size, void* d_ws, size_t ws_size,
                              hipStream_t stream) {
    const float* features = (const float*)d_in[0];   // [1,512,64,64] fp32
    const int4*  rois     = (const int4*)d_in[1];    // [R,4] int32
    float* out = (float*)d_out;
    int R = out_size / (CC * 49);                    // 1024

    if (ws_size >= (size_t)CC * HW * sizeof(float)) {
        float* ft = (float*)d_ws;                    // [HW][C], 8 MB
        transpose_kernel<<<512, 256, 0, stream>>>(features, ft);
        int ngroups = R * 8;                         // 64 channels per wave
        pool_kernel<<<ngroups / 4, 256, 0, stream>>>(ft, rois, out, ngroups);
    } else {
        int ngroups = R * 16;
        roi_pool_direct<<<(ngroups + 3) / 4, 256, 0, stream>>>(features, rois, out, ngroups);
    }
}